// Round 3
// baseline (227.187 us; speedup 1.0000x reference)
//
#include <hip/hip_runtime.h>
#include <hip/hip_bf16.h>
#include <math.h>

#define NN 512

// smearing constants
#define START 0.006737946999085467f            // exp(-5)
#define STEP  ((1.0f - START) * (1.0f/15.0f))  // linspace step
#define SB    (0.125f * (1.0f - START))
#define BETA  (1.0f/(SB*SB))
#define LOG2E 1.4426950408889634f
#define NB    (-(BETA)*LOG2E)                  // exp(-beta t^2) = exp2(NB t^2)

// ---------------------------------------------------------------------------
// k1a: stage-1 einsum partials. Grid 1024 = 256 i-tiles(x2 rows) * 4 j-chunks.
// 256 thr = 64 j-slots * 4 c-quad lanes. IT=2 keeps acc[] at 48 regs: NO SPILL
// (R2's IT=4 acc[144] spilled to scratch -> 45 MB WRITE_SIZE, 51 us).
// Output: part1[i][jc][96], 96 = kq*48 + b*16 + c.
// ---------------------------------------------------------------------------
__global__ __launch_bounds__(256,2) void k1a(const float* __restrict__ x,
                                             const float* __restrict__ W,
                                             float* __restrict__ part1)
{
    const int it = blockIdx.x >> 2, jc = blockIdx.x & 3;
    const int i0 = it * 2;
    const int tid = threadIdx.x;
    const int s = tid >> 2, l = tid & 3;
    const int lane = tid & 63, wv = tid >> 6;

    __shared__ float s_part[4][4][50];   // 48 used, pad->50 breaks bank aliasing

    float xi[2][3];
    #pragma unroll
    for (int ii = 0; ii < 2; ++ii) {
        xi[ii][0] = x[(i0+ii)*3+0];
        xi[ii][1] = x[(i0+ii)*3+1];
        xi[ii][2] = x[(i0+ii)*3+2];
    }

    float acc[48];                       // [i][kq][b][e] = i*24+kq*12+b*4+e
    #pragma unroll
    for (int v = 0; v < 48; ++v) acc[v] = 0.f;

    const int jbase = jc * 128;
    for (int jt = 0; jt < 2; ++jt) {
        const int j = jbase + jt*64 + s;
        const float xj0 = x[j*3+0], xj1 = x[j*3+1], xj2 = x[j*3+2];

        float d[2][3], cutv[2], en[2];
        #pragma unroll
        for (int ii = 0; ii < 2; ++ii) {
            float d0 = xi[ii][0]-xj0, d1 = xi[ii][1]-xj1, d2 = xi[ii][2]-xj2;
            float nsq = fmaf(d0,d0, fmaf(d1,d1, fmaf(d2,d2, 1e-6f)));
            float rs  = __builtin_amdgcn_rsqf(nsq);
            float nrm = nsq * rs;
            float inv = rs * rs;
            d[ii][0] = d0*inv; d[ii][1] = d1*inv; d[ii][2] = d2*inv;
            float cv = 0.f;
            if (nrm < 5.0f) cv = 0.5f*(__cosf(nrm*0.6283185307179586f)+1.0f);
            cutv[ii] = cv;
            en[ii]   = exp2f(-LOG2E * nrm);
        }

        const float4* kj = reinterpret_cast<const float4*>(W + j*256 + l*4);
        const float4* qj = reinterpret_cast<const float4*>(W + NN*256 + j*256 + l*4);

        float tk[2][4], tq[2][4];
        #pragma unroll
        for (int ii = 0; ii < 2; ++ii)
            #pragma unroll
            for (int e = 0; e < 4; ++e) { tk[ii][e] = 0.f; tq[ii][e] = 0.f; }

        #pragma unroll
        for (int r = 0; r < 16; ++r) {
            float4 k4 = kj[r*4];
            float4 q4 = qj[r*4];
            const float m = START + STEP * (float)r;
            #pragma unroll
            for (int ii = 0; ii < 2; ++ii) {
                float t = en[ii] - m;
                float e = exp2f(NB * t * t);
                tk[ii][0] = fmaf(e, k4.x, tk[ii][0]);
                tk[ii][1] = fmaf(e, k4.y, tk[ii][1]);
                tk[ii][2] = fmaf(e, k4.z, tk[ii][2]);
                tk[ii][3] = fmaf(e, k4.w, tk[ii][3]);
                tq[ii][0] = fmaf(e, q4.x, tq[ii][0]);
                tq[ii][1] = fmaf(e, q4.y, tq[ii][1]);
                tq[ii][2] = fmaf(e, q4.z, tq[ii][2]);
                tq[ii][3] = fmaf(e, q4.w, tq[ii][3]);
            }
        }

        #pragma unroll
        for (int ii = 0; ii < 2; ++ii) {
            const float w0 = cutv[ii]*d[ii][0];
            const float w1 = cutv[ii]*d[ii][1];
            const float w2 = cutv[ii]*d[ii][2];
            #pragma unroll
            for (int e = 0; e < 4; ++e) {
                acc[ii*24 +      e] = fmaf(w0, tk[ii][e], acc[ii*24 +      e]);
                acc[ii*24 +  4 + e] = fmaf(w1, tk[ii][e], acc[ii*24 +  4 + e]);
                acc[ii*24 +  8 + e] = fmaf(w2, tk[ii][e], acc[ii*24 +  8 + e]);
                acc[ii*24 + 12 + e] = fmaf(w0, tq[ii][e], acc[ii*24 + 12 + e]);
                acc[ii*24 + 16 + e] = fmaf(w1, tq[ii][e], acc[ii*24 + 16 + e]);
                acc[ii*24 + 20 + e] = fmaf(w2, tq[ii][e], acc[ii*24 + 20 + e]);
            }
        }
    }

    #pragma unroll
    for (int v = 0; v < 48; ++v) {
        float t = acc[v];
        t += __shfl_xor(t, 4);
        t += __shfl_xor(t, 8);
        t += __shfl_xor(t, 16);
        t += __shfl_xor(t, 32);
        if (lane < 4) s_part[wv][l][v] = t;
    }
    __syncthreads();

    for (int v = tid; v < 192; v += 256) {
        int i = v / 96, o = v - i*96;
        int kq = o / 48, rem = o - kq*48;
        int b = rem >> 4, c = rem & 15;
        int ll = c >> 2, e = c & 3;
        int f = i*24 + kq*12 + b*4 + e;
        float sum = s_part[0][ll][f] + s_part[1][ll][f]
                  + s_part[2][ll][f] + s_part[3][ll][f];
        part1[(i0+i)*384 + jc*96 + o] = sum;
    }
}

// ---------------------------------------------------------------------------
// k1b: per-i reduce partials -> att1 -> silu(W1) -> att2 row.  Grid 512.
// ---------------------------------------------------------------------------
__global__ __launch_bounds__(256) void k1b(const float* __restrict__ part1,
                                           const float* __restrict__ W1,
                                           const float* __restrict__ b1,
                                           const float* __restrict__ W2,
                                           float* __restrict__ att2)
{
    const int i = blockIdx.x;
    const int tid = threadIdx.x;
    __shared__ float s_bkq[96];
    __shared__ float s_att[256];
    __shared__ float s_z[16][16];
    __shared__ float s_a1[16];

    if (tid < 96) {
        const float* p = part1 + i*384 + tid;
        s_bkq[tid] = p[0] + p[96] + p[192] + p[288];
    }
    __syncthreads();

    {
        int h = tid >> 4, g = tid & 15;
        s_att[tid] = s_bkq[     h]*s_bkq[48+     g]
                   + s_bkq[16 + h]*s_bkq[48+16 + g]
                   + s_bkq[32 + h]*s_bkq[48+32 + g];
    }
    __syncthreads();

    {
        int h = tid & 15, seg = tid >> 4;
        const float* w1 = W1 + h*256 + seg*16;
        const float* a  = s_att + seg*16;
        float p = 0.f;
        #pragma unroll
        for (int k = 0; k < 16; ++k) p = fmaf(a[k], w1[k], p);
        s_z[seg][h] = p;
    }
    __syncthreads();

    if (tid < 16) {
        float z = b1[tid];
        #pragma unroll
        for (int seg = 0; seg < 16; ++seg) z += s_z[seg][tid];
        s_a1[tid] = z / (1.0f + __expf(-z));
    }
    __syncthreads();

    float a1[16];
    #pragma unroll
    for (int c = 0; c < 16; ++c) a1[c] = s_a1[c];
    #pragma unroll
    for (int p = 0; p < 4; ++p) {
        int o = tid + p*256;
        const float4* w2 = reinterpret_cast<const float4*>(W2 + o*16);
        float4 wa = w2[0], wb = w2[1], wc = w2[2], wd = w2[3];
        float accv = wa.x*a1[0] + wa.y*a1[1] + wa.z*a1[2] + wa.w*a1[3]
                   + wb.x*a1[4] + wb.y*a1[5] + wb.z*a1[6] + wb.w*a1[7]
                   + wc.x*a1[8] + wc.y*a1[9] + wc.z*a1[10]+ wc.w*a1[11]
                   + wd.x*a1[12]+ wd.y*a1[13]+ wd.z*a1[14]+ wd.w*a1[15];
        att2[i*1024 + o] = accv;
    }
}

// ---------------------------------------------------------------------------
// k2a: stage-3 right-term + S partials. IT=2: acc[72], no spill.
// part2[i][jc][144]: o<96 = (kq,b,c); o>=96 = S at 96 + r*3 + b.
// ---------------------------------------------------------------------------
__global__ __launch_bounds__(256,2) void k2a(const float* __restrict__ x,
                                             const float* __restrict__ att2,
                                             float* __restrict__ part2)
{
    const int it = blockIdx.x >> 2, jc = blockIdx.x & 3;
    const int i0 = it * 2;
    const int tid = threadIdx.x;
    const int s = tid >> 2, l = tid & 3;
    const int lane = tid & 63, wv = tid >> 6;

    __shared__ float s_part[4][4][74];   // 72 used

    float xi[2][3];
    #pragma unroll
    for (int ii = 0; ii < 2; ++ii) {
        xi[ii][0] = x[(i0+ii)*3+0];
        xi[ii][1] = x[(i0+ii)*3+1];
        xi[ii][2] = x[(i0+ii)*3+2];
    }

    float acc[72];                       // [i]*36: 24 bkq (kq*12+b*4+e) + 12 S (24+rl*3+b)
    #pragma unroll
    for (int v = 0; v < 72; ++v) acc[v] = 0.f;

    const int jbase = jc * 128;
    for (int jt = 0; jt < 2; ++jt) {
        const int j = jbase + jt*64 + s;
        const float xj0 = x[j*3+0], xj1 = x[j*3+1], xj2 = x[j*3+2];

        float d[2][3], cutv[2], en[2];
        #pragma unroll
        for (int ii = 0; ii < 2; ++ii) {
            float d0 = xi[ii][0]-xj0, d1 = xi[ii][1]-xj1, d2 = xi[ii][2]-xj2;
            float nsq = fmaf(d0,d0, fmaf(d1,d1, fmaf(d2,d2, 1e-6f)));
            float rs  = __builtin_amdgcn_rsqf(nsq);
            float nrm = nsq * rs;
            float inv = rs * rs;
            d[ii][0] = d0*inv; d[ii][1] = d1*inv; d[ii][2] = d2*inv;
            float cv = 0.f;
            if (nrm < 5.0f) cv = 0.5f*(__cosf(nrm*0.6283185307179586f)+1.0f);
            cutv[ii] = cv;
            en[ii]   = exp2f(-LOG2E * nrm);
        }

        const float4* rj = reinterpret_cast<const float4*>(att2 + j*1024 + 512 + l*4);

        float tk[2][4], tq[2][4];
        #pragma unroll
        for (int ii = 0; ii < 2; ++ii)
            #pragma unroll
            for (int e = 0; e < 4; ++e) { tk[ii][e] = 0.f; tq[ii][e] = 0.f; }

        #pragma unroll
        for (int r = 0; r < 16; ++r) {
            float4 k4 = rj[r*4];
            float4 q4 = rj[64 + r*4];
            const float m = START + STEP * (float)r;
            #pragma unroll
            for (int ii = 0; ii < 2; ++ii) {
                float t = en[ii] - m;
                float e = exp2f(NB * t * t);
                tk[ii][0] = fmaf(e, k4.x, tk[ii][0]);
                tk[ii][1] = fmaf(e, k4.y, tk[ii][1]);
                tk[ii][2] = fmaf(e, k4.z, tk[ii][2]);
                tk[ii][3] = fmaf(e, k4.w, tk[ii][3]);
                tq[ii][0] = fmaf(e, q4.x, tq[ii][0]);
                tq[ii][1] = fmaf(e, q4.y, tq[ii][1]);
                tq[ii][2] = fmaf(e, q4.z, tq[ii][2]);
                tq[ii][3] = fmaf(e, q4.w, tq[ii][3]);
                if ((r & 3) == l) {       // this lane owns r: S[i][r>>2][b]
                    float es = e * cutv[ii];
                    const int fb = ii*36 + 24 + (r>>2)*3;
                    acc[fb+0] = fmaf(es, d[ii][0], acc[fb+0]);
                    acc[fb+1] = fmaf(es, d[ii][1], acc[fb+1]);
                    acc[fb+2] = fmaf(es, d[ii][2], acc[fb+2]);
                }
            }
        }

        #pragma unroll
        for (int ii = 0; ii < 2; ++ii) {
            const float w0 = cutv[ii]*d[ii][0];
            const float w1 = cutv[ii]*d[ii][1];
            const float w2 = cutv[ii]*d[ii][2];
            #pragma unroll
            for (int e = 0; e < 4; ++e) {
                acc[ii*36 +      e] = fmaf(w0, tk[ii][e], acc[ii*36 +      e]);
                acc[ii*36 +  4 + e] = fmaf(w1, tk[ii][e], acc[ii*36 +  4 + e]);
                acc[ii*36 +  8 + e] = fmaf(w2, tk[ii][e], acc[ii*36 +  8 + e]);
                acc[ii*36 + 12 + e] = fmaf(w0, tq[ii][e], acc[ii*36 + 12 + e]);
                acc[ii*36 + 16 + e] = fmaf(w1, tq[ii][e], acc[ii*36 + 16 + e]);
                acc[ii*36 + 20 + e] = fmaf(w2, tq[ii][e], acc[ii*36 + 20 + e]);
            }
        }
    }

    #pragma unroll
    for (int v = 0; v < 72; ++v) {
        float t = acc[v];
        t += __shfl_xor(t, 4);
        t += __shfl_xor(t, 8);
        t += __shfl_xor(t, 16);
        t += __shfl_xor(t, 32);
        if (lane < 4) s_part[wv][l][v] = t;
    }
    __syncthreads();

    for (int v = tid; v < 288; v += 256) {
        int i = v / 144, o = v - i*144;
        int ll, f;
        if (o < 96) {
            int kq = o / 48, rem = o - kq*48;
            int b = rem >> 4, c = rem & 15;
            ll = c >> 2;
            f = i*36 + kq*12 + b*4 + (c & 3);
        } else {
            int oS = o - 96;
            int r = oS / 3, b = oS - r*3;
            ll = r & 3;
            f = i*36 + 24 + (r>>2)*3 + b;
        }
        float sum = s_part[0][ll][f] + s_part[1][ll][f]
                  + s_part[2][ll][f] + s_part[3][ll][f];
        part2[(i0+i)*576 + jc*144 + o] = sum;
    }
}

// ---------------------------------------------------------------------------
// k2b: reduce + separable left-term + att3 -> silu(W3) -> W4 -> out. Grid 512.
// ---------------------------------------------------------------------------
__global__ __launch_bounds__(256) void k2b(const float* __restrict__ att2,
                                           const float* __restrict__ part2,
                                           const float* __restrict__ W3,
                                           const float* __restrict__ b3,
                                           const float* __restrict__ W4,
                                           const float* __restrict__ b4,
                                           float* __restrict__ out)
{
    const int i = blockIdx.x;
    const int tid = threadIdx.x;
    __shared__ float s_red[144];
    __shared__ float s_att[256];
    __shared__ float s_z[16][16];
    __shared__ float s_a1[16];

    if (tid < 144) {
        const float* p = part2 + i*576 + tid;
        s_red[tid] = p[0] + p[144] + p[288] + p[432];
    }
    __syncthreads();

    if (tid < 96) {                      // left-term: bkq[c,b] += sum_r left[r,c]*S[r,b]
        int kq = tid / 48, rem = tid - kq*48;
        int b = rem >> 4, c = rem & 15;
        const float* lrow = att2 + i*1024 + kq*256 + c;
        float add = 0.f;
        #pragma unroll
        for (int r = 0; r < 16; ++r)
            add = fmaf(lrow[r*16], s_red[96 + r*3 + b], add);
        s_red[tid] += add;
    }
    __syncthreads();

    {
        int h = tid >> 4, g = tid & 15;
        s_att[tid] = s_red[     h]*s_red[48+     g]
                   + s_red[16 + h]*s_red[48+16 + g]
                   + s_red[32 + h]*s_red[48+32 + g];
    }
    __syncthreads();

    {
        int h = tid & 15, seg = tid >> 4;
        const float* w3 = W3 + h*256 + seg*16;
        const float* a  = s_att + seg*16;
        float p = 0.f;
        #pragma unroll
        for (int k = 0; k < 16; ++k) p = fmaf(a[k], w3[k], p);
        s_z[seg][h] = p;
    }
    __syncthreads();

    if (tid < 16) {
        float z = b3[tid];
        #pragma unroll
        for (int seg = 0; seg < 16; ++seg) z += s_z[seg][tid];
        s_a1[tid] = z / (1.0f + __expf(-z));
    }
    __syncthreads();

    if (tid == 0) {
        float accv = b4[0];
        #pragma unroll
        for (int c = 0; c < 16; ++c) accv = fmaf(s_a1[c], W4[c], accv);
        out[i] = accv;
    }
}

extern "C" void kernel_launch(void* const* d_in, const int* in_sizes, int n_in,
                              void* d_out, int out_size, void* d_ws, size_t ws_size,
                              hipStream_t stream) {
    (void)in_sizes; (void)n_in; (void)out_size; (void)ws_size;
    const float* x  = (const float*)d_in[0];
    const float* W  = (const float*)d_in[1];
    const float* W1 = (const float*)d_in[2];
    const float* b1 = (const float*)d_in[3];
    const float* W2 = (const float*)d_in[4];
    const float* W3 = (const float*)d_in[5];
    const float* b3 = (const float*)d_in[6];
    const float* W4 = (const float*)d_in[7];
    const float* b4 = (const float*)d_in[8];

    float* att2  = (float*)d_ws;            // 512*1024
    float* part1 = att2 + 512*1024;         // 512*384
    float* part2 = part1 + 512*384;         // 512*576
    float* out   = (float*)d_out;

    k1a<<<1024, 256, 0, stream>>>(x, W, part1);
    k1b<<<512, 256, 0, stream>>>(part1, W1, b1, W2, att2);
    k2a<<<1024, 256, 0, stream>>>(x, att2, part2);
    k2b<<<512, 256, 0, stream>>>(att2, part2, W3, b3, W4, b4, out);
}

// Round 4
// 199.268 us; speedup vs baseline: 1.1401x; 1.1401x over previous
//
#include <hip/hip_runtime.h>
#include <hip/hip_bf16.h>
#include <math.h>

#define NN 512

// smearing constants
#define START 0.006737946999085467f            // exp(-5)
#define STEP  ((1.0f - START) * (1.0f/15.0f))  // linspace step
#define SB    (0.125f * (1.0f - START))
#define BETA  (1.0f/(SB*SB))
#define LOG2E 1.4426950408889634f
#define NB    (-(BETA)*LOG2E)                  // exp(-beta t^2) = exp2(NB t^2)

// ---------------------------------------------------------------------------
// k1a: stage-1 einsum partials. IT=1: one i-row per block -> acc[24] only.
// (R2's IT=4 acc[144] and R3's IT=2 acc[48]+unrolled-load-pipeline both
//  spilled to scratch: 45-76 MB WRITE_SIZE. Per-thread state must stay
//  under ~90 VGPRs INCLUDING the in-flight float4 loads.)
// Grid 1024 = 512 i * 2 j-halves. 256 thr = 64 j-slots * 4 c-quad lanes.
// Output: part1[i][js][96], 96 = kq*48 + b*16 + c.
// ---------------------------------------------------------------------------
__global__ __launch_bounds__(256) void k1a(const float* __restrict__ x,
                                           const float* __restrict__ W,
                                           float* __restrict__ part1)
{
    const int i  = blockIdx.x >> 1;
    const int js = blockIdx.x & 1;
    const int tid = threadIdx.x;
    const int s = tid >> 2, l = tid & 3;
    const int lane = tid & 63, wv = tid >> 6;

    __shared__ float s_part[4][4][26];   // 24 used, pad->26

    const float xi0 = x[i*3+0], xi1 = x[i*3+1], xi2 = x[i*3+2];

    float acc[24];                       // kq*12 + b*4 + e
    #pragma unroll
    for (int v = 0; v < 24; ++v) acc[v] = 0.f;

    const int jbase = js * 256;
    for (int jt = 0; jt < 4; ++jt) {
        const int j = jbase + jt*64 + s;
        float d0 = xi0 - x[j*3+0];
        float d1 = xi1 - x[j*3+1];
        float d2 = xi2 - x[j*3+2];
        float nsq = fmaf(d0,d0, fmaf(d1,d1, fmaf(d2,d2, 1e-6f)));
        float rs  = __builtin_amdgcn_rsqf(nsq);
        float nrm = nsq * rs;            // sqrt
        float inv = rs * rs;             // 1/nsq
        d0 *= inv; d1 *= inv; d2 *= inv;
        float cutv = 0.f;
        if (nrm < 5.0f) cutv = 0.5f*(__cosf(nrm*0.6283185307179586f)+1.0f);
        float en = exp2f(-LOG2E * nrm);

        const float4* kj = reinterpret_cast<const float4*>(W + j*256 + l*4);
        const float4* qj = reinterpret_cast<const float4*>(W + NN*256 + j*256 + l*4);

        float tk0=0.f,tk1=0.f,tk2=0.f,tk3=0.f, tq0=0.f,tq1=0.f,tq2=0.f,tq3=0.f;
        #pragma unroll
        for (int r = 0; r < 16; ++r) {
            float4 k4 = kj[r*4];
            float4 q4 = qj[r*4];
            float t = en - (START + STEP * (float)r);
            float e = exp2f(NB * t * t);
            tk0 = fmaf(e, k4.x, tk0); tk1 = fmaf(e, k4.y, tk1);
            tk2 = fmaf(e, k4.z, tk2); tk3 = fmaf(e, k4.w, tk3);
            tq0 = fmaf(e, q4.x, tq0); tq1 = fmaf(e, q4.y, tq1);
            tq2 = fmaf(e, q4.z, tq2); tq3 = fmaf(e, q4.w, tq3);
        }

        const float w0 = cutv*d0, w1 = cutv*d1, w2 = cutv*d2;
        acc[ 0]=fmaf(w0,tk0,acc[ 0]); acc[ 1]=fmaf(w0,tk1,acc[ 1]);
        acc[ 2]=fmaf(w0,tk2,acc[ 2]); acc[ 3]=fmaf(w0,tk3,acc[ 3]);
        acc[ 4]=fmaf(w1,tk0,acc[ 4]); acc[ 5]=fmaf(w1,tk1,acc[ 5]);
        acc[ 6]=fmaf(w1,tk2,acc[ 6]); acc[ 7]=fmaf(w1,tk3,acc[ 7]);
        acc[ 8]=fmaf(w2,tk0,acc[ 8]); acc[ 9]=fmaf(w2,tk1,acc[ 9]);
        acc[10]=fmaf(w2,tk2,acc[10]); acc[11]=fmaf(w2,tk3,acc[11]);
        acc[12]=fmaf(w0,tq0,acc[12]); acc[13]=fmaf(w0,tq1,acc[13]);
        acc[14]=fmaf(w0,tq2,acc[14]); acc[15]=fmaf(w0,tq3,acc[15]);
        acc[16]=fmaf(w1,tq0,acc[16]); acc[17]=fmaf(w1,tq1,acc[17]);
        acc[18]=fmaf(w1,tq2,acc[18]); acc[19]=fmaf(w1,tq3,acc[19]);
        acc[20]=fmaf(w2,tq0,acc[20]); acc[21]=fmaf(w2,tq1,acc[21]);
        acc[22]=fmaf(w2,tq2,acc[22]); acc[23]=fmaf(w2,tq3,acc[23]);
    }

    #pragma unroll
    for (int v = 0; v < 24; ++v) {
        float t = acc[v];
        t += __shfl_xor(t, 4);
        t += __shfl_xor(t, 8);
        t += __shfl_xor(t, 16);
        t += __shfl_xor(t, 32);
        if (lane < 4) s_part[wv][l][v] = t;
    }
    __syncthreads();

    if (tid < 96) {
        int o = tid;
        int kq = o / 48, rem = o - kq*48;
        int b = rem >> 4, c = rem & 15;
        int ll = c >> 2, f = kq*12 + b*4 + (c & 3);
        float sum = s_part[0][ll][f] + s_part[1][ll][f]
                  + s_part[2][ll][f] + s_part[3][ll][f];
        part1[i*192 + js*96 + o] = sum;
    }
}

// ---------------------------------------------------------------------------
// k1b: per-i reduce partials -> att1 -> silu(W1) -> att2 row.  Grid 512.
// ---------------------------------------------------------------------------
__global__ __launch_bounds__(256) void k1b(const float* __restrict__ part1,
                                           const float* __restrict__ W1,
                                           const float* __restrict__ b1,
                                           const float* __restrict__ W2,
                                           float* __restrict__ att2)
{
    const int i = blockIdx.x;
    const int tid = threadIdx.x;
    __shared__ float s_bkq[96];
    __shared__ float s_att[256];
    __shared__ float s_z[16][16];
    __shared__ float s_a1[16];

    if (tid < 96) {
        const float* p = part1 + i*192 + tid;
        s_bkq[tid] = p[0] + p[96];
    }
    __syncthreads();

    {
        int h = tid >> 4, g = tid & 15;
        s_att[tid] = s_bkq[     h]*s_bkq[48+     g]
                   + s_bkq[16 + h]*s_bkq[48+16 + g]
                   + s_bkq[32 + h]*s_bkq[48+32 + g];
    }
    __syncthreads();

    {
        int h = tid & 15, seg = tid >> 4;
        const float* w1 = W1 + h*256 + seg*16;
        const float* a  = s_att + seg*16;
        float p = 0.f;
        #pragma unroll
        for (int k = 0; k < 16; ++k) p = fmaf(a[k], w1[k], p);
        s_z[seg][h] = p;
    }
    __syncthreads();

    if (tid < 16) {
        float z = b1[tid];
        #pragma unroll
        for (int seg = 0; seg < 16; ++seg) z += s_z[seg][tid];
        s_a1[tid] = z / (1.0f + __expf(-z));
    }
    __syncthreads();

    float a1[16];
    #pragma unroll
    for (int c = 0; c < 16; ++c) a1[c] = s_a1[c];
    #pragma unroll
    for (int p = 0; p < 4; ++p) {
        int o = tid + p*256;
        const float4* w2 = reinterpret_cast<const float4*>(W2 + o*16);
        float4 wa = w2[0], wb = w2[1], wc = w2[2], wd = w2[3];
        float accv = wa.x*a1[0] + wa.y*a1[1] + wa.z*a1[2] + wa.w*a1[3]
                   + wb.x*a1[4] + wb.y*a1[5] + wb.z*a1[6] + wb.w*a1[7]
                   + wc.x*a1[8] + wc.y*a1[9] + wc.z*a1[10]+ wc.w*a1[11]
                   + wd.x*a1[12]+ wd.y*a1[13]+ wd.z*a1[14]+ wd.w*a1[15];
        att2[i*1024 + o] = accv;
    }
}

// ---------------------------------------------------------------------------
// k2a: stage-3 right-term + S partials. IT=1: acc[36].
// part2[i][js][144]: o<96 = (kq,b,c); o>=96 = S at 96 + r*3 + b.
// ---------------------------------------------------------------------------
__global__ __launch_bounds__(256) void k2a(const float* __restrict__ x,
                                           const float* __restrict__ att2,
                                           float* __restrict__ part2)
{
    const int i  = blockIdx.x >> 1;
    const int js = blockIdx.x & 1;
    const int tid = threadIdx.x;
    const int s = tid >> 2, l = tid & 3;
    const int lane = tid & 63, wv = tid >> 6;

    __shared__ float s_part[4][4][38];   // 36 used

    const float xi0 = x[i*3+0], xi1 = x[i*3+1], xi2 = x[i*3+2];

    float acc[36];                       // 24 bkq (kq*12+b*4+e) + 12 S (24+rl*3+b)
    #pragma unroll
    for (int v = 0; v < 36; ++v) acc[v] = 0.f;

    const int jbase = js * 256;
    for (int jt = 0; jt < 4; ++jt) {
        const int j = jbase + jt*64 + s;
        float d0 = xi0 - x[j*3+0];
        float d1 = xi1 - x[j*3+1];
        float d2 = xi2 - x[j*3+2];
        float nsq = fmaf(d0,d0, fmaf(d1,d1, fmaf(d2,d2, 1e-6f)));
        float rs  = __builtin_amdgcn_rsqf(nsq);
        float nrm = nsq * rs;
        float inv = rs * rs;
        d0 *= inv; d1 *= inv; d2 *= inv;
        float cutv = 0.f;
        if (nrm < 5.0f) cutv = 0.5f*(__cosf(nrm*0.6283185307179586f)+1.0f);
        float en = exp2f(-LOG2E * nrm);

        const float4* rj = reinterpret_cast<const float4*>(att2 + j*1024 + 512 + l*4);

        float tk0=0.f,tk1=0.f,tk2=0.f,tk3=0.f, tq0=0.f,tq1=0.f,tq2=0.f,tq3=0.f;
        #pragma unroll
        for (int r = 0; r < 16; ++r) {
            float4 k4 = rj[r*4];
            float4 q4 = rj[64 + r*4];
            float t = en - (START + STEP * (float)r);
            float e = exp2f(NB * t * t);
            tk0 = fmaf(e, k4.x, tk0); tk1 = fmaf(e, k4.y, tk1);
            tk2 = fmaf(e, k4.z, tk2); tk3 = fmaf(e, k4.w, tk3);
            tq0 = fmaf(e, q4.x, tq0); tq1 = fmaf(e, q4.y, tq1);
            tq2 = fmaf(e, q4.z, tq2); tq3 = fmaf(e, q4.w, tq3);
            if ((r & 3) == l) {          // this lane owns r: S[r>>2][b]
                float es = e * cutv;
                const int fb = 24 + (r>>2)*3;
                acc[fb+0] = fmaf(es, d0, acc[fb+0]);
                acc[fb+1] = fmaf(es, d1, acc[fb+1]);
                acc[fb+2] = fmaf(es, d2, acc[fb+2]);
            }
        }

        const float w0 = cutv*d0, w1 = cutv*d1, w2 = cutv*d2;
        acc[ 0]=fmaf(w0,tk0,acc[ 0]); acc[ 1]=fmaf(w0,tk1,acc[ 1]);
        acc[ 2]=fmaf(w0,tk2,acc[ 2]); acc[ 3]=fmaf(w0,tk3,acc[ 3]);
        acc[ 4]=fmaf(w1,tk0,acc[ 4]); acc[ 5]=fmaf(w1,tk1,acc[ 5]);
        acc[ 6]=fmaf(w1,tk2,acc[ 6]); acc[ 7]=fmaf(w1,tk3,acc[ 7]);
        acc[ 8]=fmaf(w2,tk0,acc[ 8]); acc[ 9]=fmaf(w2,tk1,acc[ 9]);
        acc[10]=fmaf(w2,tk2,acc[10]); acc[11]=fmaf(w2,tk3,acc[11]);
        acc[12]=fmaf(w0,tq0,acc[12]); acc[13]=fmaf(w0,tq1,acc[13]);
        acc[14]=fmaf(w0,tq2,acc[14]); acc[15]=fmaf(w0,tq3,acc[15]);
        acc[16]=fmaf(w1,tq0,acc[16]); acc[17]=fmaf(w1,tq1,acc[17]);
        acc[18]=fmaf(w1,tq2,acc[18]); acc[19]=fmaf(w1,tq3,acc[19]);
        acc[20]=fmaf(w2,tq0,acc[20]); acc[21]=fmaf(w2,tq1,acc[21]);
        acc[22]=fmaf(w2,tq2,acc[22]); acc[23]=fmaf(w2,tq3,acc[23]);
    }

    #pragma unroll
    for (int v = 0; v < 36; ++v) {
        float t = acc[v];
        t += __shfl_xor(t, 4);
        t += __shfl_xor(t, 8);
        t += __shfl_xor(t, 16);
        t += __shfl_xor(t, 32);
        if (lane < 4) s_part[wv][l][v] = t;
    }
    __syncthreads();

    if (tid < 144) {
        int o = tid;
        int ll, f;
        if (o < 96) {
            int kq = o / 48, rem = o - kq*48;
            int b = rem >> 4, c = rem & 15;
            ll = c >> 2;
            f = kq*12 + b*4 + (c & 3);
        } else {
            int oS = o - 96;
            int r = oS / 3, b = oS - r*3;
            ll = r & 3;
            f = 24 + (r>>2)*3 + b;
        }
        float sum = s_part[0][ll][f] + s_part[1][ll][f]
                  + s_part[2][ll][f] + s_part[3][ll][f];
        part2[i*288 + js*144 + o] = sum;
    }
}

// ---------------------------------------------------------------------------
// k2b: reduce + separable left-term + att3 -> silu(W3) -> W4 -> out. Grid 512.
// ---------------------------------------------------------------------------
__global__ __launch_bounds__(256) void k2b(const float* __restrict__ att2,
                                           const float* __restrict__ part2,
                                           const float* __restrict__ W3,
                                           const float* __restrict__ b3,
                                           const float* __restrict__ W4,
                                           const float* __restrict__ b4,
                                           float* __restrict__ out)
{
    const int i = blockIdx.x;
    const int tid = threadIdx.x;
    __shared__ float s_red[144];
    __shared__ float s_att[256];
    __shared__ float s_z[16][16];
    __shared__ float s_a1[16];

    if (tid < 144) {
        const float* p = part2 + i*288 + tid;
        s_red[tid] = p[0] + p[144];
    }
    __syncthreads();

    if (tid < 96) {                      // left-term: bkq[c,b] += sum_r left[r,c]*S[r,b]
        int kq = tid / 48, rem = tid - kq*48;
        int b = rem >> 4, c = rem & 15;
        const float* lrow = att2 + i*1024 + kq*256 + c;
        float add = 0.f;
        #pragma unroll
        for (int r = 0; r < 16; ++r)
            add = fmaf(lrow[r*16], s_red[96 + r*3 + b], add);
        s_red[tid] += add;
    }
    __syncthreads();

    {
        int h = tid >> 4, g = tid & 15;
        s_att[tid] = s_red[     h]*s_red[48+     g]
                   + s_red[16 + h]*s_red[48+16 + g]
                   + s_red[32 + h]*s_red[48+32 + g];
    }
    __syncthreads();

    {
        int h = tid & 15, seg = tid >> 4;
        const float* w3 = W3 + h*256 + seg*16;
        const float* a  = s_att + seg*16;
        float p = 0.f;
        #pragma unroll
        for (int k = 0; k < 16; ++k) p = fmaf(a[k], w3[k], p);
        s_z[seg][h] = p;
    }
    __syncthreads();

    if (tid < 16) {
        float z = b3[tid];
        #pragma unroll
        for (int seg = 0; seg < 16; ++seg) z += s_z[seg][tid];
        s_a1[tid] = z / (1.0f + __expf(-z));
    }
    __syncthreads();

    if (tid == 0) {
        float accv = b4[0];
        #pragma unroll
        for (int c = 0; c < 16; ++c) accv = fmaf(s_a1[c], W4[c], accv);
        out[i] = accv;
    }
}

extern "C" void kernel_launch(void* const* d_in, const int* in_sizes, int n_in,
                              void* d_out, int out_size, void* d_ws, size_t ws_size,
                              hipStream_t stream) {
    (void)in_sizes; (void)n_in; (void)out_size; (void)ws_size;
    const float* x  = (const float*)d_in[0];
    const float* W  = (const float*)d_in[1];
    const float* W1 = (const float*)d_in[2];
    const float* b1 = (const float*)d_in[3];
    const float* W2 = (const float*)d_in[4];
    const float* W3 = (const float*)d_in[5];
    const float* b3 = (const float*)d_in[6];
    const float* W4 = (const float*)d_in[7];
    const float* b4 = (const float*)d_in[8];

    float* att2  = (float*)d_ws;            // 512*1024
    float* part1 = att2 + 512*1024;         // 512*192
    float* part2 = part1 + 512*192;         // 512*288
    float* out   = (float*)d_out;

    k1a<<<1024, 256, 0, stream>>>(x, W, part1);
    k1b<<<512, 256, 0, stream>>>(part1, W1, b1, W2, att2);
    k2a<<<1024, 256, 0, stream>>>(x, att2, part2);
    k2b<<<512, 256, 0, stream>>>(att2, part2, W3, b3, W4, b4, out);
}

// Round 5
// 143.299 us; speedup vs baseline: 1.5854x; 1.3906x over previous
//
#include <hip/hip_runtime.h>
#include <hip/hip_bf16.h>
#include <math.h>

#define NN 512

// smearing constants
#define START 0.006737946999085467f            // exp(-5)
#define STEP  ((1.0f - START) * (1.0f/15.0f))  // linspace step
#define SB    (0.125f * (1.0f - START))
#define BETA  (1.0f/(SB*SB))
#define LOG2E 1.4426950408889634f
#define NB    (-(BETA)*LOG2E)                  // exp(-beta t^2) = exp2(NB t^2)

// ===========================================================================
// R5 structure: LDS-staged tiles. R2/R3/R4 all spilled because the fully
// unrolled r-loop kept 32 float4 GLOBAL loads in flight (128+ VGPRs).
// Now: cooperative stage of a 16-j tile of K/Q (or att2-right) into LDS
// (8 float4/thread, bounded), smearing G computed once per (i,j,r) into LDS,
// contraction reads LDS only. IT=4 i-rows per block reuse every staged byte
// and every exp 4x; j-parallelism = 16 slots so acc stays at 24-36 regs.
// Block: 256 thr = 16 j-slots x 16 c-lanes. Grid: 128 i-tiles x 2 j-halves.
// ===========================================================================

// ---------------------------------------------------------------------------
// k1a: stage-1 einsum partials. part1[i][jsH][96], 96 = kq*48 + b*16 + c.
// ---------------------------------------------------------------------------
__global__ __launch_bounds__(256) void k1a(const float* __restrict__ x,
                                           const float* __restrict__ W,
                                           float* __restrict__ part1)
{
    const int ib = blockIdx.x >> 1, jsH = blockIdx.x & 1;
    const int i0 = ib * 4;
    const int tid = threadIdx.x;
    const int c = tid & 15, js = tid >> 4;     // contract-phase role
    const int lane = tid & 63, wv = tid >> 6;

    __shared__ float lK[16*272];               // [j][r][c] stride 17 per r
    __shared__ float lQ[16*272];
    __shared__ float lG[4*272];                // [i][j][r] stride 17 per j
    __shared__ float lD[192];                  // [i][j][b]
    __shared__ float s_part[4][16][26];        // [wave][c][24]

    // G-phase role
    const int gi = tid >> 6, gj = (tid >> 2) & 15, grq = tid & 3;
    const float gxi0 = x[(i0+gi)*3+0];
    const float gxi1 = x[(i0+gi)*3+1];
    const float gxi2 = x[(i0+gi)*3+2];

    float acc[24];                             // [i][kq][b] = i*6+kq*3+b
    #pragma unroll
    for (int v = 0; v < 24; ++v) acc[v] = 0.f;

    for (int jt = 0; jt < 16; ++jt) {
        const int jb = jsH*256 + jt*16;
        __syncthreads();                       // prev tile fully consumed

        // ---- stage K/Q tile: 2048 float4, 8 per thread ----
        #pragma unroll
        for (int k = 0; k < 8; ++k) {
            int idx = tid + k*256;             // 0..2047
            int arr = idx >> 10, rem = idx & 1023;
            int j = rem >> 6, q = rem & 63;
            int r = q >> 2, cq = q & 3;
            float4 v4 = *reinterpret_cast<const float4*>(
                W + arr*NN*256 + (jb+j)*256 + r*16 + cq*4);
            float* dst = (arr ? lQ : lK) + j*272 + r*17 + cq*4;
            dst[0]=v4.x; dst[1]=v4.y; dst[2]=v4.z; dst[3]=v4.w;
        }

        // ---- G-phase: geometry + smearing for (gi, gj), 4 r's ----
        {
            float d0 = gxi0 - x[(jb+gj)*3+0];
            float d1 = gxi1 - x[(jb+gj)*3+1];
            float d2 = gxi2 - x[(jb+gj)*3+2];
            float nsq = fmaf(d0,d0, fmaf(d1,d1, fmaf(d2,d2, 1e-6f)));
            float rs  = __builtin_amdgcn_rsqf(nsq);
            float nrm = nsq * rs;
            float inv = rs * rs;
            float cutv = 0.f;
            if (nrm < 5.0f) cutv = 0.5f*(__cosf(nrm*0.6283185307179586f)+1.0f);
            float en = exp2f(-LOG2E * nrm);
            if (grq == 0) {
                lD[(gi*16+gj)*3+0] = d0*inv;
                lD[(gi*16+gj)*3+1] = d1*inv;
                lD[(gi*16+gj)*3+2] = d2*inv;
            }
            #pragma unroll
            for (int k = 0; k < 4; ++k) {
                int r = grq*4 + k;
                float t = en - (START + STEP*(float)r);
                lG[gi*272 + gj*17 + r] = cutv * exp2f(NB*t*t);
            }
        }
        __syncthreads();

        // ---- contract: thread (c, js) over its j ----
        float kk[16], qq[16];
        #pragma unroll
        for (int r = 0; r < 16; ++r) {
            kk[r] = lK[js*272 + r*17 + c];
            qq[r] = lQ[js*272 + r*17 + c];
        }
        #pragma unroll
        for (int i = 0; i < 4; ++i) {
            float tk = 0.f, tq = 0.f;
            #pragma unroll
            for (int r = 0; r < 16; ++r) {
                float g = lG[i*272 + js*17 + r];   // broadcast across c-lanes
                tk = fmaf(g, kk[r], tk);
                tq = fmaf(g, qq[r], tq);
            }
            float dd0 = lD[(i*16+js)*3+0];
            float dd1 = lD[(i*16+js)*3+1];
            float dd2 = lD[(i*16+js)*3+2];
            acc[i*6+0] = fmaf(tk, dd0, acc[i*6+0]);
            acc[i*6+1] = fmaf(tk, dd1, acc[i*6+1]);
            acc[i*6+2] = fmaf(tk, dd2, acc[i*6+2]);
            acc[i*6+3] = fmaf(tq, dd0, acc[i*6+3]);
            acc[i*6+4] = fmaf(tq, dd1, acc[i*6+4]);
            acc[i*6+5] = fmaf(tq, dd2, acc[i*6+5]);
        }
    }

    // reduce over 16 j-slots: js bits 0,1 are lane bits 4,5; js bits 2,3 = wave
    #pragma unroll
    for (int v = 0; v < 24; ++v) {
        float t = acc[v];
        t += __shfl_xor(t, 16);
        t += __shfl_xor(t, 32);
        if (lane < 16) s_part[wv][c][v] = t;
    }
    __syncthreads();

    for (int v = tid; v < 384; v += 256) {
        int i = v / 96, o = v - i*96;
        int kq = o / 48, rem = o - kq*48;
        int b = rem >> 4, c2 = rem & 15;
        int f = i*6 + kq*3 + b;
        float sum = s_part[0][c2][f] + s_part[1][c2][f]
                  + s_part[2][c2][f] + s_part[3][c2][f];
        part1[(i0+i)*192 + jsH*96 + o] = sum;
    }
}

// ---------------------------------------------------------------------------
// k1b: per-i reduce partials -> att1 -> silu(W1) -> att2 row.  Grid 512.
// ---------------------------------------------------------------------------
__global__ __launch_bounds__(256) void k1b(const float* __restrict__ part1,
                                           const float* __restrict__ W1,
                                           const float* __restrict__ b1,
                                           const float* __restrict__ W2,
                                           float* __restrict__ att2)
{
    const int i = blockIdx.x;
    const int tid = threadIdx.x;
    __shared__ float s_bkq[96];
    __shared__ float s_att[256];
    __shared__ float s_z[16][16];
    __shared__ float s_a1[16];

    if (tid < 96) {
        const float* p = part1 + i*192 + tid;
        s_bkq[tid] = p[0] + p[96];
    }
    __syncthreads();

    {
        int h = tid >> 4, g = tid & 15;
        s_att[tid] = s_bkq[     h]*s_bkq[48+     g]
                   + s_bkq[16 + h]*s_bkq[48+16 + g]
                   + s_bkq[32 + h]*s_bkq[48+32 + g];
    }
    __syncthreads();

    {
        int h = tid & 15, seg = tid >> 4;
        const float* w1 = W1 + h*256 + seg*16;
        const float* a  = s_att + seg*16;
        float p = 0.f;
        #pragma unroll
        for (int k = 0; k < 16; ++k) p = fmaf(a[k], w1[k], p);
        s_z[seg][h] = p;
    }
    __syncthreads();

    if (tid < 16) {
        float z = b1[tid];
        #pragma unroll
        for (int seg = 0; seg < 16; ++seg) z += s_z[seg][tid];
        s_a1[tid] = z / (1.0f + __expf(-z));
    }
    __syncthreads();

    float a1[16];
    #pragma unroll
    for (int c = 0; c < 16; ++c) a1[c] = s_a1[c];
    #pragma unroll
    for (int p = 0; p < 4; ++p) {
        int o = tid + p*256;
        const float4* w2 = reinterpret_cast<const float4*>(W2 + o*16);
        float4 wa = w2[0], wb = w2[1], wc = w2[2], wd = w2[3];
        float accv = wa.x*a1[0] + wa.y*a1[1] + wa.z*a1[2] + wa.w*a1[3]
                   + wb.x*a1[4] + wb.y*a1[5] + wb.z*a1[6] + wb.w*a1[7]
                   + wc.x*a1[8] + wc.y*a1[9] + wc.z*a1[10]+ wc.w*a1[11]
                   + wd.x*a1[12]+ wd.y*a1[13]+ wd.z*a1[14]+ wd.w*a1[15];
        att2[i*1024 + o] = accv;
    }
}

// ---------------------------------------------------------------------------
// k2a: stage-3 right-term + S partials, same LDS-staged structure.
// part2[i][jsH][144]: o<96 = (kq,b,c); o>=96 = S at 96 + r*3 + b.
// ---------------------------------------------------------------------------
__global__ __launch_bounds__(256) void k2a(const float* __restrict__ x,
                                           const float* __restrict__ att2,
                                           float* __restrict__ part2)
{
    const int ib = blockIdx.x >> 1, jsH = blockIdx.x & 1;
    const int i0 = ib * 4;
    const int tid = threadIdx.x;
    const int c = tid & 15, js = tid >> 4;
    const int lane = tid & 63, wv = tid >> 6;

    __shared__ float lK[16*272];               // right_k tile
    __shared__ float lQ[16*272];               // right_q tile
    __shared__ float lG[4*272];
    __shared__ float lD[192];
    __shared__ float s_part[4][16][38];        // [wave][c][36]

    const int gi = tid >> 6, gj = (tid >> 2) & 15, grq = tid & 3;
    const float gxi0 = x[(i0+gi)*3+0];
    const float gxi1 = x[(i0+gi)*3+1];
    const float gxi2 = x[(i0+gi)*3+2];

    float acc[36];                             // 24 main + 12 S (24+i*3+b, r=c)
    #pragma unroll
    for (int v = 0; v < 36; ++v) acc[v] = 0.f;

    for (int jt = 0; jt < 16; ++jt) {
        const int jb = jsH*256 + jt*16;
        __syncthreads();

        #pragma unroll
        for (int k = 0; k < 8; ++k) {
            int idx = tid + k*256;
            int arr = idx >> 10, rem = idx & 1023;
            int j = rem >> 6, q = rem & 63;
            int r = q >> 2, cq = q & 3;
            float4 v4 = *reinterpret_cast<const float4*>(
                att2 + (jb+j)*1024 + 512 + arr*256 + r*16 + cq*4);
            float* dst = (arr ? lQ : lK) + j*272 + r*17 + cq*4;
            dst[0]=v4.x; dst[1]=v4.y; dst[2]=v4.z; dst[3]=v4.w;
        }

        {
            float d0 = gxi0 - x[(jb+gj)*3+0];
            float d1 = gxi1 - x[(jb+gj)*3+1];
            float d2 = gxi2 - x[(jb+gj)*3+2];
            float nsq = fmaf(d0,d0, fmaf(d1,d1, fmaf(d2,d2, 1e-6f)));
            float rs  = __builtin_amdgcn_rsqf(nsq);
            float nrm = nsq * rs;
            float inv = rs * rs;
            float cutv = 0.f;
            if (nrm < 5.0f) cutv = 0.5f*(__cosf(nrm*0.6283185307179586f)+1.0f);
            float en = exp2f(-LOG2E * nrm);
            if (grq == 0) {
                lD[(gi*16+gj)*3+0] = d0*inv;
                lD[(gi*16+gj)*3+1] = d1*inv;
                lD[(gi*16+gj)*3+2] = d2*inv;
            }
            #pragma unroll
            for (int k = 0; k < 4; ++k) {
                int r = grq*4 + k;
                float t = en - (START + STEP*(float)r);
                lG[gi*272 + gj*17 + r] = cutv * exp2f(NB*t*t);
            }
        }
        __syncthreads();

        float kk[16], qq[16];
        #pragma unroll
        for (int r = 0; r < 16; ++r) {
            kk[r] = lK[js*272 + r*17 + c];
            qq[r] = lQ[js*272 + r*17 + c];
        }
        #pragma unroll
        for (int i = 0; i < 4; ++i) {
            float tk = 0.f, tq = 0.f;
            #pragma unroll
            for (int r = 0; r < 16; ++r) {
                float g = lG[i*272 + js*17 + r];
                tk = fmaf(g, kk[r], tk);
                tq = fmaf(g, qq[r], tq);
            }
            float dd0 = lD[(i*16+js)*3+0];
            float dd1 = lD[(i*16+js)*3+1];
            float dd2 = lD[(i*16+js)*3+2];
            acc[i*6+0] = fmaf(tk, dd0, acc[i*6+0]);
            acc[i*6+1] = fmaf(tk, dd1, acc[i*6+1]);
            acc[i*6+2] = fmaf(tk, dd2, acc[i*6+2]);
            acc[i*6+3] = fmaf(tq, dd0, acc[i*6+3]);
            acc[i*6+4] = fmaf(tq, dd1, acc[i*6+4]);
            acc[i*6+5] = fmaf(tq, dd2, acc[i*6+5]);
            float gc = lG[i*272 + js*17 + c];      // this lane's r=c for S
            acc[24+i*3+0] = fmaf(gc, dd0, acc[24+i*3+0]);
            acc[24+i*3+1] = fmaf(gc, dd1, acc[24+i*3+1]);
            acc[24+i*3+2] = fmaf(gc, dd2, acc[24+i*3+2]);
        }
    }

    #pragma unroll
    for (int v = 0; v < 36; ++v) {
        float t = acc[v];
        t += __shfl_xor(t, 16);
        t += __shfl_xor(t, 32);
        if (lane < 16) s_part[wv][c][v] = t;
    }
    __syncthreads();

    for (int v = tid; v < 576; v += 256) {
        int i = v / 144, o = v - i*144;
        int c2, f;
        if (o < 96) {
            int kq = o / 48, rem = o - kq*48;
            int b = rem >> 4; c2 = rem & 15;
            f = i*6 + kq*3 + b;
        } else {
            int oS = o - 96;
            int r = oS / 3, b = oS - r*3;
            c2 = r;
            f = 24 + i*3 + b;
        }
        float sum = s_part[0][c2][f] + s_part[1][c2][f]
                  + s_part[2][c2][f] + s_part[3][c2][f];
        part2[(i0+i)*288 + jsH*144 + o] = sum;
    }
}

// ---------------------------------------------------------------------------
// k2b: reduce + separable left-term + att3 -> silu(W3) -> W4 -> out. Grid 512.
// ---------------------------------------------------------------------------
__global__ __launch_bounds__(256) void k2b(const float* __restrict__ att2,
                                           const float* __restrict__ part2,
                                           const float* __restrict__ W3,
                                           const float* __restrict__ b3,
                                           const float* __restrict__ W4,
                                           const float* __restrict__ b4,
                                           float* __restrict__ out)
{
    const int i = blockIdx.x;
    const int tid = threadIdx.x;
    __shared__ float s_red[144];
    __shared__ float s_att[256];
    __shared__ float s_z[16][16];
    __shared__ float s_a1[16];

    if (tid < 144) {
        const float* p = part2 + i*288 + tid;
        s_red[tid] = p[0] + p[144];
    }
    __syncthreads();

    if (tid < 96) {                      // left-term: bkq[c,b] += sum_r left[r,c]*S[r,b]
        int kq = tid / 48, rem = tid - kq*48;
        int b = rem >> 4, c = rem & 15;
        const float* lrow = att2 + i*1024 + kq*256 + c;
        float add = 0.f;
        #pragma unroll
        for (int r = 0; r < 16; ++r)
            add = fmaf(lrow[r*16], s_red[96 + r*3 + b], add);
        s_red[tid] += add;
    }
    __syncthreads();

    {
        int h = tid >> 4, g = tid & 15;
        s_att[tid] = s_red[     h]*s_red[48+     g]
                   + s_red[16 + h]*s_red[48+16 + g]
                   + s_red[32 + h]*s_red[48+32 + g];
    }
    __syncthreads();

    {
        int h = tid & 15, seg = tid >> 4;
        const float* w3 = W3 + h*256 + seg*16;
        const float* a  = s_att + seg*16;
        float p = 0.f;
        #pragma unroll
        for (int k = 0; k < 16; ++k) p = fmaf(a[k], w3[k], p);
        s_z[seg][h] = p;
    }
    __syncthreads();

    if (tid < 16) {
        float z = b3[tid];
        #pragma unroll
        for (int seg = 0; seg < 16; ++seg) z += s_z[seg][tid];
        s_a1[tid] = z / (1.0f + __expf(-z));
    }
    __syncthreads();

    if (tid == 0) {
        float accv = b4[0];
        #pragma unroll
        for (int c = 0; c < 16; ++c) accv = fmaf(s_a1[c], W4[c], accv);
        out[i] = accv;
    }
}

extern "C" void kernel_launch(void* const* d_in, const int* in_sizes, int n_in,
                              void* d_out, int out_size, void* d_ws, size_t ws_size,
                              hipStream_t stream) {
    (void)in_sizes; (void)n_in; (void)out_size; (void)ws_size;
    const float* x  = (const float*)d_in[0];
    const float* W  = (const float*)d_in[1];
    const float* W1 = (const float*)d_in[2];
    const float* b1 = (const float*)d_in[3];
    const float* W2 = (const float*)d_in[4];
    const float* W3 = (const float*)d_in[5];
    const float* b3 = (const float*)d_in[6];
    const float* W4 = (const float*)d_in[7];
    const float* b4 = (const float*)d_in[8];

    float* att2  = (float*)d_ws;            // 512*1024
    float* part1 = att2 + 512*1024;         // 512*192
    float* part2 = part1 + 512*192;         // 512*288
    float* out   = (float*)d_out;

    k1a<<<256, 256, 0, stream>>>(x, W, part1);
    k1b<<<512, 256, 0, stream>>>(part1, W1, b1, W2, att2);
    k2a<<<256, 256, 0, stream>>>(x, att2, part2);
    k2b<<<512, 256, 0, stream>>>(att2, part2, W3, b3, W4, b4, out);
}

// Round 6
// 126.040 us; speedup vs baseline: 1.8025x; 1.1369x over previous
//
#include <hip/hip_runtime.h>
#include <hip/hip_bf16.h>
#include <math.h>

#define NN 512

// smearing constants
#define START 0.006737946999085467f            // exp(-5)
#define STEP  ((1.0f - START) * (1.0f/15.0f))  // linspace step
#define SB    (0.125f * (1.0f - START))
#define BETA  (1.0f/(SB*SB))
#define LOG2E 1.4426950408889634f
#define NB    (-(BETA)*LOG2E)                  // exp(-beta t^2) = exp2(NB t^2)

// ===========================================================================
// R6: LDS-pipe relief. R5 was LDS-issue-bound (~800 LDS-cyc/wave-tile on the
// one LDS pipe/CU). Changes:
//  - kk/qq read DIRECT from global (scalar stride-64B, one read/element/block,
//    VMEM pipe) -- no staging writes, no LDS reads for K/Q.
//  - G broadcast + D kept in LDS but b128-vectorized (4 reads/i instead of 16).
//  - jsplit=8, grid 1024 (4 blocks/CU), ib-fast indexing so co-resident
//    blocks share the same j-tile in L1.
// Block: 256 thr = 16 j-slots x 16 c-lanes; IT=4 i-rows; 4 tiles of 16 j.
// ===========================================================================

// ---------------------------------------------------------------------------
// k1a: stage-1 einsum partials. part1[i][jsH][96], 96 = kq*48 + b*16 + c.
// ---------------------------------------------------------------------------
__global__ __launch_bounds__(256) void k1a(const float* __restrict__ x,
                                           const float* __restrict__ W,
                                           float* __restrict__ part1)
{
    const int ib = blockIdx.x & 127, jsH = blockIdx.x >> 7;
    const int i0 = ib * 4;
    const int tid = threadIdx.x;
    const int c = tid & 15, js = tid >> 4;
    const int lane = tid & 63, wv = tid >> 6;

    __shared__ float lG[1328];                 // i*328 + js*20 + r
    __shared__ float lP[256];                  // (i*16+js)*4 + {d0,d1,d2,pad}
    __shared__ float s_part[4][16][26];

    const int gi = tid >> 6, gj = (tid >> 2) & 15, grq = tid & 3;
    const float gxi0 = x[(i0+gi)*3+0];
    const float gxi1 = x[(i0+gi)*3+1];
    const float gxi2 = x[(i0+gi)*3+2];

    float acc[24];                             // i*6 + kq*3 + b
    #pragma unroll
    for (int v = 0; v < 24; ++v) acc[v] = 0.f;

    for (int jt = 0; jt < 4; ++jt) {
        const int jb = jsH*64 + jt*16;
        __syncthreads();                       // lG/lP consumed

        // ---- G phase: one (gi,gj), 4 r's per thread ----
        {
            float d0 = gxi0 - x[(jb+gj)*3+0];
            float d1 = gxi1 - x[(jb+gj)*3+1];
            float d2 = gxi2 - x[(jb+gj)*3+2];
            float nsq = fmaf(d0,d0, fmaf(d1,d1, fmaf(d2,d2, 1e-6f)));
            float rs  = __builtin_amdgcn_rsqf(nsq);
            float nrm = nsq * rs;
            float inv = rs * rs;
            float cutv = 0.f;
            if (nrm < 5.0f) cutv = 0.5f*(__cosf(nrm*0.6283185307179586f)+1.0f);
            float en = exp2f(-LOG2E * nrm);
            if (grq == 0) {
                float4 dP; dP.x = d0*inv; dP.y = d1*inv; dP.z = d2*inv; dP.w = 0.f;
                *reinterpret_cast<float4*>(&lP[(gi*16+gj)*4]) = dP;
            }
            float4 g4;
            {
                float t0 = en - (START + STEP*(float)(grq*4+0));
                float t1 = en - (START + STEP*(float)(grq*4+1));
                float t2 = en - (START + STEP*(float)(grq*4+2));
                float t3 = en - (START + STEP*(float)(grq*4+3));
                g4.x = cutv * exp2f(NB*t0*t0);
                g4.y = cutv * exp2f(NB*t1*t1);
                g4.z = cutv * exp2f(NB*t2*t2);
                g4.w = cutv * exp2f(NB*t3*t3);
            }
            *reinterpret_cast<float4*>(&lG[gi*328 + gj*20 + grq*4]) = g4;
        }
        __syncthreads();

        // ---- contract: direct global kk/qq (one element per thread each) ----
        const float* Kr = W + (size_t)(jb+js)*256 + c;
        const float* Qr = Kr + NN*256;
        float kk[16], qq[16];
        #pragma unroll
        for (int r = 0; r < 16; ++r) { kk[r] = Kr[r*16]; qq[r] = Qr[r*16]; }

        #pragma unroll
        for (int i = 0; i < 4; ++i) {
            const float4* gp = reinterpret_cast<const float4*>(&lG[i*328 + js*20]);
            float4 gA = gp[0], gB = gp[1], gC = gp[2], gD = gp[3];
            float tk = 0.f, tq = 0.f;
            tk = fmaf(gA.x,kk[ 0], tk); tq = fmaf(gA.x,qq[ 0], tq);
            tk = fmaf(gA.y,kk[ 1], tk); tq = fmaf(gA.y,qq[ 1], tq);
            tk = fmaf(gA.z,kk[ 2], tk); tq = fmaf(gA.z,qq[ 2], tq);
            tk = fmaf(gA.w,kk[ 3], tk); tq = fmaf(gA.w,qq[ 3], tq);
            tk = fmaf(gB.x,kk[ 4], tk); tq = fmaf(gB.x,qq[ 4], tq);
            tk = fmaf(gB.y,kk[ 5], tk); tq = fmaf(gB.y,qq[ 5], tq);
            tk = fmaf(gB.z,kk[ 6], tk); tq = fmaf(gB.z,qq[ 6], tq);
            tk = fmaf(gB.w,kk[ 7], tk); tq = fmaf(gB.w,qq[ 7], tq);
            tk = fmaf(gC.x,kk[ 8], tk); tq = fmaf(gC.x,qq[ 8], tq);
            tk = fmaf(gC.y,kk[ 9], tk); tq = fmaf(gC.y,qq[ 9], tq);
            tk = fmaf(gC.z,kk[10], tk); tq = fmaf(gC.z,qq[10], tq);
            tk = fmaf(gC.w,kk[11], tk); tq = fmaf(gC.w,qq[11], tq);
            tk = fmaf(gD.x,kk[12], tk); tq = fmaf(gD.x,qq[12], tq);
            tk = fmaf(gD.y,kk[13], tk); tq = fmaf(gD.y,qq[13], tq);
            tk = fmaf(gD.z,kk[14], tk); tq = fmaf(gD.z,qq[14], tq);
            tk = fmaf(gD.w,kk[15], tk); tq = fmaf(gD.w,qq[15], tq);
            float4 dd = *reinterpret_cast<const float4*>(&lP[(i*16+js)*4]);
            acc[i*6+0] = fmaf(tk, dd.x, acc[i*6+0]);
            acc[i*6+1] = fmaf(tk, dd.y, acc[i*6+1]);
            acc[i*6+2] = fmaf(tk, dd.z, acc[i*6+2]);
            acc[i*6+3] = fmaf(tq, dd.x, acc[i*6+3]);
            acc[i*6+4] = fmaf(tq, dd.y, acc[i*6+4]);
            acc[i*6+5] = fmaf(tq, dd.z, acc[i*6+5]);
        }
    }

    // reduce over 16 j-slots (js bits 0,1 = lane bits 4,5; bits 2,3 = wave)
    #pragma unroll
    for (int v = 0; v < 24; ++v) {
        float t = acc[v];
        t += __shfl_xor(t, 16);
        t += __shfl_xor(t, 32);
        if (lane < 16) s_part[wv][c][v] = t;
    }
    __syncthreads();

    for (int v = tid; v < 384; v += 256) {
        int i = v / 96, o = v - i*96;
        int kq = o / 48, rem = o - kq*48;
        int b = rem >> 4, c2 = rem & 15;
        int f = i*6 + kq*3 + b;
        float sum = s_part[0][c2][f] + s_part[1][c2][f]
                  + s_part[2][c2][f] + s_part[3][c2][f];
        part1[(i0+i)*768 + jsH*96 + o] = sum;
    }
}

// ---------------------------------------------------------------------------
// k1b: reduce 8 partials -> att1 -> silu(W1) -> att2 row.  Grid 512.
// ---------------------------------------------------------------------------
__global__ __launch_bounds__(256) void k1b(const float* __restrict__ part1,
                                           const float* __restrict__ W1,
                                           const float* __restrict__ b1,
                                           const float* __restrict__ W2,
                                           float* __restrict__ att2)
{
    const int i = blockIdx.x;
    const int tid = threadIdx.x;
    __shared__ float s_bkq[96];
    __shared__ float s_att[256];
    __shared__ float s_z[16][16];
    __shared__ float s_a1[16];

    if (tid < 96) {
        const float* p = part1 + i*768 + tid;
        float s = 0.f;
        #pragma unroll
        for (int k = 0; k < 8; ++k) s += p[k*96];
        s_bkq[tid] = s;
    }
    __syncthreads();

    {
        int h = tid >> 4, g = tid & 15;
        s_att[tid] = s_bkq[     h]*s_bkq[48+     g]
                   + s_bkq[16 + h]*s_bkq[48+16 + g]
                   + s_bkq[32 + h]*s_bkq[48+32 + g];
    }
    __syncthreads();

    {
        int h = tid & 15, seg = tid >> 4;
        const float* w1 = W1 + h*256 + seg*16;
        const float* a  = s_att + seg*16;
        float p = 0.f;
        #pragma unroll
        for (int k = 0; k < 16; ++k) p = fmaf(a[k], w1[k], p);
        s_z[seg][h] = p;
    }
    __syncthreads();

    if (tid < 16) {
        float z = b1[tid];
        #pragma unroll
        for (int seg = 0; seg < 16; ++seg) z += s_z[seg][tid];
        s_a1[tid] = z / (1.0f + __expf(-z));
    }
    __syncthreads();

    float a1[16];
    #pragma unroll
    for (int cc = 0; cc < 16; ++cc) a1[cc] = s_a1[cc];
    #pragma unroll
    for (int p = 0; p < 4; ++p) {
        int o = tid + p*256;
        const float4* w2 = reinterpret_cast<const float4*>(W2 + o*16);
        float4 wa = w2[0], wb = w2[1], wc = w2[2], wd = w2[3];
        float accv = wa.x*a1[0] + wa.y*a1[1] + wa.z*a1[2] + wa.w*a1[3]
                   + wb.x*a1[4] + wb.y*a1[5] + wb.z*a1[6] + wb.w*a1[7]
                   + wc.x*a1[8] + wc.y*a1[9] + wc.z*a1[10]+ wc.w*a1[11]
                   + wd.x*a1[12]+ wd.y*a1[13]+ wd.z*a1[14]+ wd.w*a1[15];
        att2[i*1024 + o] = accv;
    }
}

// ---------------------------------------------------------------------------
// k2a: stage-3 right-term + S partials, same direct-VMEM structure.
// part2[i][jsH][144]: o<96 = (kq,b,c); o>=96 = S at 96 + r*3 + b.
// ---------------------------------------------------------------------------
__global__ __launch_bounds__(256) void k2a(const float* __restrict__ x,
                                           const float* __restrict__ att2,
                                           float* __restrict__ part2)
{
    const int ib = blockIdx.x & 127, jsH = blockIdx.x >> 7;
    const int i0 = ib * 4;
    const int tid = threadIdx.x;
    const int c = tid & 15, js = tid >> 4;
    const int lane = tid & 63, wv = tid >> 6;

    __shared__ float lG[1328];
    __shared__ float lP[256];
    __shared__ float s_part[4][16][38];

    const int gi = tid >> 6, gj = (tid >> 2) & 15, grq = tid & 3;
    const float gxi0 = x[(i0+gi)*3+0];
    const float gxi1 = x[(i0+gi)*3+1];
    const float gxi2 = x[(i0+gi)*3+2];

    float acc[36];                             // 24 main + 12 S (24+i*3+b, r=c)
    #pragma unroll
    for (int v = 0; v < 36; ++v) acc[v] = 0.f;

    for (int jt = 0; jt < 4; ++jt) {
        const int jb = jsH*64 + jt*16;
        __syncthreads();

        {
            float d0 = gxi0 - x[(jb+gj)*3+0];
            float d1 = gxi1 - x[(jb+gj)*3+1];
            float d2 = gxi2 - x[(jb+gj)*3+2];
            float nsq = fmaf(d0,d0, fmaf(d1,d1, fmaf(d2,d2, 1e-6f)));
            float rs  = __builtin_amdgcn_rsqf(nsq);
            float nrm = nsq * rs;
            float inv = rs * rs;
            float cutv = 0.f;
            if (nrm < 5.0f) cutv = 0.5f*(__cosf(nrm*0.6283185307179586f)+1.0f);
            float en = exp2f(-LOG2E * nrm);
            if (grq == 0) {
                float4 dP; dP.x = d0*inv; dP.y = d1*inv; dP.z = d2*inv; dP.w = 0.f;
                *reinterpret_cast<float4*>(&lP[(gi*16+gj)*4]) = dP;
            }
            float4 g4;
            {
                float t0 = en - (START + STEP*(float)(grq*4+0));
                float t1 = en - (START + STEP*(float)(grq*4+1));
                float t2 = en - (START + STEP*(float)(grq*4+2));
                float t3 = en - (START + STEP*(float)(grq*4+3));
                g4.x = cutv * exp2f(NB*t0*t0);
                g4.y = cutv * exp2f(NB*t1*t1);
                g4.z = cutv * exp2f(NB*t2*t2);
                g4.w = cutv * exp2f(NB*t3*t3);
            }
            *reinterpret_cast<float4*>(&lG[gi*328 + gj*20 + grq*4]) = g4;
        }
        __syncthreads();

        const float* Rk = att2 + (size_t)(jb+js)*1024 + 512 + c;
        const float* Rq = Rk + 256;
        float kk[16], qq[16];
        #pragma unroll
        for (int r = 0; r < 16; ++r) { kk[r] = Rk[r*16]; qq[r] = Rq[r*16]; }

        #pragma unroll
        for (int i = 0; i < 4; ++i) {
            const float4* gp = reinterpret_cast<const float4*>(&lG[i*328 + js*20]);
            float4 gA = gp[0], gB = gp[1], gC = gp[2], gD = gp[3];
            float tk = 0.f, tq = 0.f;
            tk = fmaf(gA.x,kk[ 0], tk); tq = fmaf(gA.x,qq[ 0], tq);
            tk = fmaf(gA.y,kk[ 1], tk); tq = fmaf(gA.y,qq[ 1], tq);
            tk = fmaf(gA.z,kk[ 2], tk); tq = fmaf(gA.z,qq[ 2], tq);
            tk = fmaf(gA.w,kk[ 3], tk); tq = fmaf(gA.w,qq[ 3], tq);
            tk = fmaf(gB.x,kk[ 4], tk); tq = fmaf(gB.x,qq[ 4], tq);
            tk = fmaf(gB.y,kk[ 5], tk); tq = fmaf(gB.y,qq[ 5], tq);
            tk = fmaf(gB.z,kk[ 6], tk); tq = fmaf(gB.z,qq[ 6], tq);
            tk = fmaf(gB.w,kk[ 7], tk); tq = fmaf(gB.w,qq[ 7], tq);
            tk = fmaf(gC.x,kk[ 8], tk); tq = fmaf(gC.x,qq[ 8], tq);
            tk = fmaf(gC.y,kk[ 9], tk); tq = fmaf(gC.y,qq[ 9], tq);
            tk = fmaf(gC.z,kk[10], tk); tq = fmaf(gC.z,qq[10], tq);
            tk = fmaf(gC.w,kk[11], tk); tq = fmaf(gC.w,qq[11], tq);
            tk = fmaf(gD.x,kk[12], tk); tq = fmaf(gD.x,qq[12], tq);
            tk = fmaf(gD.y,kk[13], tk); tq = fmaf(gD.y,qq[13], tq);
            tk = fmaf(gD.z,kk[14], tk); tq = fmaf(gD.z,qq[14], tq);
            tk = fmaf(gD.w,kk[15], tk); tq = fmaf(gD.w,qq[15], tq);
            float4 dd = *reinterpret_cast<const float4*>(&lP[(i*16+js)*4]);
            acc[i*6+0] = fmaf(tk, dd.x, acc[i*6+0]);
            acc[i*6+1] = fmaf(tk, dd.y, acc[i*6+1]);
            acc[i*6+2] = fmaf(tk, dd.z, acc[i*6+2]);
            acc[i*6+3] = fmaf(tq, dd.x, acc[i*6+3]);
            acc[i*6+4] = fmaf(tq, dd.y, acc[i*6+4]);
            acc[i*6+5] = fmaf(tq, dd.z, acc[i*6+5]);
            float gc = lG[i*328 + js*20 + c];  // this lane's r=c for S
            acc[24+i*3+0] = fmaf(gc, dd.x, acc[24+i*3+0]);
            acc[24+i*3+1] = fmaf(gc, dd.y, acc[24+i*3+1]);
            acc[24+i*3+2] = fmaf(gc, dd.z, acc[24+i*3+2]);
        }
    }

    #pragma unroll
    for (int v = 0; v < 36; ++v) {
        float t = acc[v];
        t += __shfl_xor(t, 16);
        t += __shfl_xor(t, 32);
        if (lane < 16) s_part[wv][c][v] = t;
    }
    __syncthreads();

    for (int v = tid; v < 576; v += 256) {
        int i = v / 144, o = v - i*144;
        int c2, f;
        if (o < 96) {
            int kq = o / 48, rem = o - kq*48;
            int b = rem >> 4; c2 = rem & 15;
            f = i*6 + kq*3 + b;
        } else {
            int oS = o - 96;
            int r = oS / 3, b = oS - r*3;
            c2 = r;
            f = 24 + i*3 + b;
        }
        float sum = s_part[0][c2][f] + s_part[1][c2][f]
                  + s_part[2][c2][f] + s_part[3][c2][f];
        part2[(i0+i)*1152 + jsH*144 + o] = sum;
    }
}

// ---------------------------------------------------------------------------
// k2b: reduce 8 partials + separable left-term + att3 -> silu(W3) -> out.
// ---------------------------------------------------------------------------
__global__ __launch_bounds__(256) void k2b(const float* __restrict__ att2,
                                           const float* __restrict__ part2,
                                           const float* __restrict__ W3,
                                           const float* __restrict__ b3,
                                           const float* __restrict__ W4,
                                           const float* __restrict__ b4,
                                           float* __restrict__ out)
{
    const int i = blockIdx.x;
    const int tid = threadIdx.x;
    __shared__ float s_red[144];
    __shared__ float s_att[256];
    __shared__ float s_z[16][16];
    __shared__ float s_a1[16];

    if (tid < 144) {
        const float* p = part2 + i*1152 + tid;
        float s = 0.f;
        #pragma unroll
        for (int k = 0; k < 8; ++k) s += p[k*144];
        s_red[tid] = s;
    }
    __syncthreads();

    if (tid < 96) {                      // left-term: bkq[c,b] += sum_r left[r,c]*S[r,b]
        int kq = tid / 48, rem = tid - kq*48;
        int b = rem >> 4, c = rem & 15;
        const float* lrow = att2 + i*1024 + kq*256 + c;
        float add = 0.f;
        #pragma unroll
        for (int r = 0; r < 16; ++r)
            add = fmaf(lrow[r*16], s_red[96 + r*3 + b], add);
        s_red[tid] += add;
    }
    __syncthreads();

    {
        int h = tid >> 4, g = tid & 15;
        s_att[tid] = s_red[     h]*s_red[48+     g]
                   + s_red[16 + h]*s_red[48+16 + g]
                   + s_red[32 + h]*s_red[48+32 + g];
    }
    __syncthreads();

    {
        int h = tid & 15, seg = tid >> 4;
        const float* w3 = W3 + h*256 + seg*16;
        const float* a  = s_att + seg*16;
        float p = 0.f;
        #pragma unroll
        for (int k = 0; k < 16; ++k) p = fmaf(a[k], w3[k], p);
        s_z[seg][h] = p;
    }
    __syncthreads();

    if (tid < 16) {
        float z = b3[tid];
        #pragma unroll
        for (int seg = 0; seg < 16; ++seg) z += s_z[seg][tid];
        s_a1[tid] = z / (1.0f + __expf(-z));
    }
    __syncthreads();

    if (tid == 0) {
        float accv = b4[0];
        #pragma unroll
        for (int cc = 0; cc < 16; ++cc) accv = fmaf(s_a1[cc], W4[cc], accv);
        out[i] = accv;
    }
}

extern "C" void kernel_launch(void* const* d_in, const int* in_sizes, int n_in,
                              void* d_out, int out_size, void* d_ws, size_t ws_size,
                              hipStream_t stream) {
    (void)in_sizes; (void)n_in; (void)out_size; (void)ws_size;
    const float* x  = (const float*)d_in[0];
    const float* W  = (const float*)d_in[1];
    const float* W1 = (const float*)d_in[2];
    const float* b1 = (const float*)d_in[3];
    const float* W2 = (const float*)d_in[4];
    const float* W3 = (const float*)d_in[5];
    const float* b3 = (const float*)d_in[6];
    const float* W4 = (const float*)d_in[7];
    const float* b4 = (const float*)d_in[8];

    float* att2  = (float*)d_ws;            // 512*1024
    float* part1 = att2 + 512*1024;         // 512*768
    float* part2 = part1 + 512*768;         // 512*1152
    float* out   = (float*)d_out;

    k1a<<<1024, 256, 0, stream>>>(x, W, part1);
    k1b<<<512, 256, 0, stream>>>(part1, W1, b1, W2, att2);
    k2a<<<1024, 256, 0, stream>>>(x, att2, part2);
    k2b<<<512, 256, 0, stream>>>(att2, part2, W3, b3, W4, b4, out);
}